// Round 1
// baseline (4313.823 us; speedup 1.0000x reference)
//
#include <hip/hip_runtime.h>
#include <hip/hip_bf16.h>
#include <math.h>

// LSTMEncoder: B=32 A=64 T=128 N_IN=6 N_EMB=128 N_H=256, E=256, N=B*A=2048 rows
// Fold: W_comb[1024][6] = W_ih @ W_emb ; b_comb = W_ih @ b_emb + b_ih + b_hh
// Recurrent: rows independent -> 256 blocks x 8 rows, full T-loop per block, no grid sync.

#define T_   128
#define NIN  6
#define NH   256
#define NG   1024   // 4*NH
#define E_   256

// ws layout (float offsets)
#define WS_W4 0        // [4][64][256][4] = W_hh[q*256+j][kb*4+ki]  (262144 floats)
#define WS_WC 262144   // [4][6][256]: Wc[q][f][j]                  (6144 floats)
#define WS_BC 268288   // [4][256]:    bc[q][j]                     (1024 floats)

__global__ void prep_kernel(const float* __restrict__ W_emb, const float* __restrict__ b_emb,
                            const float* __restrict__ W_ih,  const float* __restrict__ W_hh,
                            const float* __restrict__ b_ih,  const float* __restrict__ b_hh,
                            float* __restrict__ ws)
{
    int tid = blockIdx.x * blockDim.x + threadIdx.x;   // 0..65535
    // --- transpose W_hh -> W4[q][kb][j][ki] ---
    {
        int kb = tid & 63;
        int j  = (tid >> 6) & 255;
        int q  = tid >> 14;
        int g  = q * 256 + j;
        const float4 w = *reinterpret_cast<const float4*>(&W_hh[g * 256 + kb * 4]);
        *reinterpret_cast<float4*>(&ws[WS_W4 + (((q * 64 + kb) * 256 + j) << 2)]) = w;
    }
    // --- fold input path: W_comb, b_comb ---
    if (tid < NG) {
        int g = tid;
        float accf[NIN] = {0.f, 0.f, 0.f, 0.f, 0.f, 0.f};
        float accb = 0.f;
        for (int e = 0; e < E_; ++e) {
            float w = W_ih[g * E_ + e];
            accb += w * b_emb[e];
            #pragma unroll
            for (int f = 0; f < NIN; ++f) accf[f] += w * W_emb[e * NIN + f];
        }
        int q = g >> 8, j = g & 255;
        #pragma unroll
        for (int f = 0; f < NIN; ++f) ws[WS_WC + (q * NIN + f) * 256 + j] = accf[f];
        ws[WS_BC + g] = accb + b_ih[g] + b_hh[g];
    }
}

__device__ __forceinline__ float sigmoidf_(float x) { return 1.f / (1.f + __expf(-x)); }
__device__ __forceinline__ float tanhf_(float x) {
    // overflow-safe: exp(-2|x|) in (0,1]
    float e = __expf(-2.f * fabsf(x));
    float r = (1.f - e) / (1.f + e);
    return copysignf(r, x);
}

__global__ __launch_bounds__(512)
void lstm_main(const float* __restrict__ xin, const float* __restrict__ ws,
               float* __restrict__ out)
{
    __shared__ float hsh[8][256];   // 8 KB: h state for this block's 8 rows
    __shared__ float xsh[8][NIN];

    const int tid = threadIdx.x;    // 0..511
    const int j   = tid & 255;      // hidden unit owned by this thread
    const int rh  = tid >> 8;       // row-half: rows rh*4 .. rh*4+3
    const int n0  = blockIdx.x * 8; // first batch row of this block

    const float*  Wc = ws + WS_WC;
    const float*  bc = ws + WS_BC;
    const float4* W4 = reinterpret_cast<const float4*>(ws + WS_W4); // [4][64][256] float4

    // input-path weights for this thread's 4 gates (i,f,g,o of unit j) -> registers
    float wc[4][NIN], bcr[4];
    #pragma unroll
    for (int q = 0; q < 4; ++q) {
        #pragma unroll
        for (int f = 0; f < NIN; ++f) wc[q][f] = Wc[(q * NIN + f) * 256 + j];
        bcr[q] = bc[q * 256 + j];
    }

    float cst[4] = {0.f, 0.f, 0.f, 0.f};  // cell state, 4 rows
    for (int i = tid; i < 8 * 256; i += 512) (&hsh[0][0])[i] = 0.f;
    __syncthreads();

    const float4* hp0 = reinterpret_cast<const float4*>(&hsh[rh * 4][0]); // rows as [4][64] float4

    for (int t = 0; t < T_; ++t) {
        // stage x[t] for the 8 rows (48 floats)
        if (tid < 48) {
            int r = tid / NIN, f = tid - r * NIN;
            xsh[r][f] = xin[((n0 + r) * T_ + t) * NIN + f];
        }

        float acc[4][4];
        #pragma unroll
        for (int r = 0; r < 4; ++r)
            #pragma unroll
            for (int q = 0; q < 4; ++q) acc[r][q] = 0.f;

        // K-loop: gates[r][q] += sum_k h[r][k] * W_hh[q*256+j][k]
        #pragma unroll 2
        for (int kb = 0; kb < 64; ++kb) {
            float4 w0 = W4[(0 * 64 + kb) * 256 + j];
            float4 w1 = W4[(1 * 64 + kb) * 256 + j];
            float4 w2 = W4[(2 * 64 + kb) * 256 + j];
            float4 w3 = W4[(3 * 64 + kb) * 256 + j];
            #pragma unroll
            for (int r = 0; r < 4; ++r) {
                float4 hv = hp0[r * 64 + kb];  // LDS broadcast
                acc[r][0] = fmaf(hv.x, w0.x, fmaf(hv.y, w0.y, fmaf(hv.z, w0.z, fmaf(hv.w, w0.w, acc[r][0]))));
                acc[r][1] = fmaf(hv.x, w1.x, fmaf(hv.y, w1.y, fmaf(hv.z, w1.z, fmaf(hv.w, w1.w, acc[r][1]))));
                acc[r][2] = fmaf(hv.x, w2.x, fmaf(hv.y, w2.y, fmaf(hv.z, w2.z, fmaf(hv.w, w2.w, acc[r][2]))));
                acc[r][3] = fmaf(hv.x, w3.x, fmaf(hv.y, w3.y, fmaf(hv.z, w3.z, fmaf(hv.w, w3.w, acc[r][3]))));
            }
        }
        __syncthreads();   // h reads done; xsh visible

        #pragma unroll
        for (int r = 0; r < 4; ++r) {
            float pre0 = bcr[0], pre1 = bcr[1], pre2 = bcr[2], pre3 = bcr[3];
            #pragma unroll
            for (int f = 0; f < NIN; ++f) {
                float xv = xsh[rh * 4 + r][f];
                pre0 = fmaf(wc[0][f], xv, pre0);
                pre1 = fmaf(wc[1][f], xv, pre1);
                pre2 = fmaf(wc[2][f], xv, pre2);
                pre3 = fmaf(wc[3][f], xv, pre3);
            }
            float gi = sigmoidf_(acc[r][0] + pre0);
            float gf = sigmoidf_(acc[r][1] + pre1);
            float gg = tanhf_  (acc[r][2] + pre2);
            float go = sigmoidf_(acc[r][3] + pre3);
            float cn = fmaf(gf, cst[r], gi * gg);
            cst[r] = cn;
            float hn = go * tanhf_(cn);
            hsh[rh * 4 + r][j] = hn;
            out[((n0 + rh * 4 + r) * T_ + t) * NH + j] = hn;
        }
        __syncthreads();   // new h visible for next step
    }
}

extern "C" void kernel_launch(void* const* d_in, const int* in_sizes, int n_in,
                              void* d_out, int out_size, void* d_ws, size_t ws_size,
                              hipStream_t stream)
{
    const float* xin   = (const float*)d_in[0];
    const float* W_emb = (const float*)d_in[1];
    const float* b_emb = (const float*)d_in[2];
    const float* W_ih  = (const float*)d_in[3];
    const float* W_hh  = (const float*)d_in[4];
    const float* b_ih  = (const float*)d_in[5];
    const float* b_hh  = (const float*)d_in[6];
    float* out = (float*)d_out;
    float* ws  = (float*)d_ws;

    prep_kernel<<<256, 256, 0, stream>>>(W_emb, b_emb, W_ih, W_hh, b_ih, b_hh, ws);
    lstm_main<<<256, 512, 0, stream>>>(xin, ws, out);
}

// Round 2
// 1891.209 us; speedup vs baseline: 2.2810x; 2.2810x over previous
//
#include <hip/hip_runtime.h>
#include <math.h>

// LSTMEncoder: N=2048 rows, T=128, H=256, gates=1024, E folded away.
// W_comb[1024][6] = W_ih@W_emb ; b_comb = W_ih@b_emb + b_ih + b_hh.
// Main: 128 blocks x 16 rows, 8 waves/block, full T-loop per block, 1 barrier/step.
// Recurrent GEMM via mfma_f32_16x16x32_bf16; W_hh pre-packed into per-fragment
// layout (bf16) with gate-interleaved column ordering so each lane owns all 4
// gates (i,f,g,o) of one hidden unit -> lane-local cell update.

#define T_  128
#define NH  256

typedef __attribute__((ext_vector_type(4))) float f32x4;
typedef __attribute__((ext_vector_type(8))) short s16x8;

// ws layout (bytes):
//   [0, 524288)            : wsW  — 512 fragments x 64 lanes x 8 bf16 (ushort)
//   [524288, 524288+24576) : wcP  — [q*6+f][256] fp32 folded input weights
//   [548864, 548864+4096)  : bcP  — [q][256] fp32 folded bias
#define WSW_BYTES 524288
#define WC_FLOATS 6144

__device__ __forceinline__ unsigned short f2bf(float x) {
    unsigned u = __float_as_uint(x);
    unsigned r = (u + 0x7FFFu + ((u >> 16) & 1u)) >> 16;
    return (unsigned short)r;
}

__global__ void prep(const float* __restrict__ W_emb, const float* __restrict__ b_emb,
                     const float* __restrict__ W_ih,  const float* __restrict__ W_hh,
                     const float* __restrict__ b_ih,  const float* __restrict__ b_hh,
                     unsigned short* __restrict__ wsW, float* __restrict__ wcP,
                     float* __restrict__ bcP)
{
    int tid = blockIdx.x * 256 + threadIdx.x;
    if (tid < 32768) {
        // one thread = one (fragment, lane) slot: 8 bf16 = 16B
        int l   = tid & 63;
        int fid = tid >> 6;          // 0..511
        int kt  = fid & 7;
        int ntg = fid >> 3;          // N-tile 0..63
        int q   = ntg & 3;           // gate quadrant (i,f,g,o)
        int jg  = ntg >> 2;          // j-group 0..15
        int g   = q * 256 + jg * 16 + (l & 15);   // original W_hh row
        int k0  = kt * 32 + (l >> 4) * 8;
        const float* src = &W_hh[g * 256 + k0];
        union { unsigned short u16[8]; uint4 v; } pk;
        #pragma unroll
        for (int i = 0; i < 8; ++i) pk.u16[i] = f2bf(src[i]);
        *reinterpret_cast<uint4*>(&wsW[(size_t)fid * 512 + l * 8]) = pk.v;
    } else if (tid < 32768 + 1024) {
        int g = tid - 32768;         // gate row 0..1023
        float accf[6] = {0.f, 0.f, 0.f, 0.f, 0.f, 0.f};
        float accb = 0.f;
        for (int e = 0; e < 256; ++e) {
            float w = W_ih[g * 256 + e];
            accb += w * b_emb[e];
            #pragma unroll
            for (int f = 0; f < 6; ++f) accf[f] += w * W_emb[e * 6 + f];
        }
        int q = g >> 8, j = g & 255;
        #pragma unroll
        for (int f = 0; f < 6; ++f) wcP[(q * 6 + f) * 256 + j] = accf[f];
        bcP[q * 256 + j] = accb + b_ih[g] + b_hh[g];
    }
}

__device__ __forceinline__ float sigmoidf_(float x) { return 1.f / (1.f + __expf(-x)); }
__device__ __forceinline__ float tanhf_(float x) {
    float e = __expf(-2.f * fabsf(x));
    float r = (1.f - e) / (1.f + e);
    return copysignf(r, x);
}

__global__ __launch_bounds__(512)
void lstm_main(const float* __restrict__ xin, const unsigned short* __restrict__ wsW,
               const float* __restrict__ wcP, const float* __restrict__ bcP,
               float* __restrict__ out)
{
    // h double-buffered, rows padded to 264 bf16 (+16B) -> 2-way-max bank aliasing
    __shared__ __align__(16) unsigned short hsh[2][16][264];
    __shared__ float xsh[2][16][6];

    const int tid = threadIdx.x;
    const int w   = tid >> 6;       // wave 0..7
    const int l   = tid & 63;
    const int l16 = l & 15;
    const int lg  = l >> 4;         // 0..3
    const int n0  = blockIdx.x * 16;

    // loop-invariant input-path weights -> registers (lane-local j per half)
    float wc[2][4][6], bc[2][4];
    #pragma unroll
    for (int hh = 0; hh < 2; ++hh) {
        int j = (w + 8 * hh) * 16 + l16;
        #pragma unroll
        for (int q = 0; q < 4; ++q) {
            #pragma unroll
            for (int f = 0; f < 6; ++f) wc[hh][q][f] = wcP[(q * 6 + f) * 256 + j];
            bc[hh][q] = bcP[q * 256 + j];
        }
    }

    float cst[2][4] = {{0.f,0.f,0.f,0.f},{0.f,0.f,0.f,0.f}};

    for (int i = tid; i < 2 * 16 * 264; i += 512) (&hsh[0][0][0])[i] = 0;
    if (tid < 96) { int r = tid / 6, f = tid - r * 6;
                    xsh[0][r][f] = xin[((n0 + r) * T_ + 0) * 6 + f]; }
    __syncthreads();

    #pragma unroll 1
    for (int t = 0; t < T_; ++t) {
        const int cur = t & 1, nxt = cur ^ 1;

        // prestage x[t+1]
        if (t + 1 < T_ && tid < 96) {
            int r = tid / 6, f = tid - r * 6;
            xsh[nxt][r][f] = xin[((n0 + r) * T_ + (t + 1)) * 6 + f];
        }

        f32x4 acc[2][4];
        #pragma unroll
        for (int hh = 0; hh < 2; ++hh)
            #pragma unroll
            for (int q = 0; q < 4; ++q) acc[hh][q] = (f32x4){0.f, 0.f, 0.f, 0.f};

        // ---- recurrent GEMM: gates += h @ W_hh^T (per-wave 8 N-tiles x 8 K-tiles)
        #pragma unroll
        for (int kt = 0; kt < 8; ++kt) {
            s16x8 a = *reinterpret_cast<const s16x8*>(&hsh[cur][l16][kt * 32 + lg * 8]);
            #pragma unroll
            for (int hh = 0; hh < 2; ++hh) {
                #pragma unroll
                for (int q = 0; q < 4; ++q) {
                    const int fid = (((w + 8 * hh) * 4 + q) * 8 + kt);
                    s16x8 b = *reinterpret_cast<const s16x8*>(&wsW[(size_t)fid * 512 + l * 8]);
                    acc[hh][q] = __builtin_amdgcn_mfma_f32_16x16x32_bf16(a, b, acc[hh][q], 0, 0, 0);
                }
            }
        }

        // ---- lane-local elementwise: rows m = lg*4+r, unit j, all 4 gates in-lane
        #pragma unroll
        for (int hh = 0; hh < 2; ++hh) {
            const int j = (w + 8 * hh) * 16 + l16;
            #pragma unroll
            for (int r = 0; r < 4; ++r) {
                const int m = lg * 4 + r;
                float pre0 = bc[hh][0], pre1 = bc[hh][1], pre2 = bc[hh][2], pre3 = bc[hh][3];
                #pragma unroll
                for (int f = 0; f < 6; ++f) {
                    float xv = xsh[cur][m][f];
                    pre0 = fmaf(wc[hh][0][f], xv, pre0);
                    pre1 = fmaf(wc[hh][1][f], xv, pre1);
                    pre2 = fmaf(wc[hh][2][f], xv, pre2);
                    pre3 = fmaf(wc[hh][3][f], xv, pre3);
                }
                float gi = sigmoidf_(acc[hh][0][r] + pre0);
                float gf = sigmoidf_(acc[hh][1][r] + pre1);
                float gg = tanhf_  (acc[hh][2][r] + pre2);
                float go = sigmoidf_(acc[hh][3][r] + pre3);
                float cn = fmaf(gf, cst[hh][r], gi * gg);
                cst[hh][r] = cn;
                float hn = go * tanhf_(cn);
                out[((size_t)(n0 + m) * T_ + t) * NH + j] = hn;
                hsh[nxt][m][j] = f2bf(hn);
            }
        }
        __syncthreads();   // h(t), x(t+1) visible for next step
    }
}

extern "C" void kernel_launch(void* const* d_in, const int* in_sizes, int n_in,
                              void* d_out, int out_size, void* d_ws, size_t ws_size,
                              hipStream_t stream)
{
    const float* xin   = (const float*)d_in[0];
    const float* W_emb = (const float*)d_in[1];
    const float* b_emb = (const float*)d_in[2];
    const float* W_ih  = (const float*)d_in[3];
    const float* W_hh  = (const float*)d_in[4];
    const float* b_ih  = (const float*)d_in[5];
    const float* b_hh  = (const float*)d_in[6];
    float* out = (float*)d_out;

    unsigned short* wsW = (unsigned short*)d_ws;
    float* wcP = (float*)((char*)d_ws + WSW_BYTES);
    float* bcP = wcP + WC_FLOATS;

    prep<<<132, 256, 0, stream>>>(W_emb, b_emb, W_ih, W_hh, b_ih, b_hh, wsW, wcP, bcP);
    lstm_main<<<128, 512, 0, stream>>>(xin, wsW, wcP, bcP, out);
}